// Round 1
// baseline (806.762 us; speedup 1.0000x reference)
//
#include <hip/hip_runtime.h>

#define NN 65536
#define NE 262144
#define NG 2048

// ---------------- gate logits: g_all[n] = (relu(x@gw1+gb1))@gw2 + gb2 --------
__global__ __launch_bounds__(256) void k_gate(const float* __restrict__ x,
    const float* __restrict__ gw1, const float* __restrict__ gb1,
    const float* __restrict__ gw2, const float* __restrict__ gb2,
    float* __restrict__ g_all)
{
    __shared__ float s_w[256];
    __shared__ float s_b[16];
    __shared__ float s_w2[16];
    __shared__ float s_b2;
    int tid = threadIdx.x;
    s_w[tid & 255] = gw1[tid & 255];
    if (tid < 16) { s_b[tid] = gb1[tid]; s_w2[tid] = gw2[tid]; }
    if (tid == 0) s_b2 = gb2[0];
    __syncthreads();
    int n = blockIdx.x * 256 + tid;
    if (n >= NN) return;
    float xv[16];
    const float4* xp = (const float4*)(x + (size_t)n * 16);
#pragma unroll
    for (int i = 0; i < 4; ++i) {
        float4 t = xp[i];
        xv[4*i] = t.x; xv[4*i+1] = t.y; xv[4*i+2] = t.z; xv[4*i+3] = t.w;
    }
    float g = s_b2;
#pragma unroll
    for (int j = 0; j < 16; ++j) {
        float a = s_b[j];
#pragma unroll
        for (int i = 0; i < 16; ++i) a += xv[i] * s_w[i*16 + j];
        g += fmaxf(a, 0.f) * s_w2[j];
    }
    g_all[n] = g;
}

// ---------------- graph boundary offsets (batch is sorted) ------------------
__global__ void k_offsets(const int* __restrict__ batch, int* __restrict__ offs)
{
    int g = blockIdx.x * blockDim.x + threadIdx.x;
    if (g > NG) return;
    int lo = 0, hi = NN;
    while (lo < hi) {
        int mid = (lo + hi) >> 1;
        if (batch[mid] < g) lo = mid + 1; else hi = mid;
    }
    offs[g] = lo;
}

// ---------------- attention pool over raw x ---------------------------------
__global__ __launch_bounds__(64) void k_attpool(const float* __restrict__ x,
    const float* __restrict__ g_all, const int* __restrict__ offs,
    float* __restrict__ x_att)
{
    int g = blockIdx.x;
    int lane = threadIdx.x;
    int s = offs[g], e = offs[g + 1];
    if (s >= e) {
        if (lane < 16) x_att[g*16 + lane] = 0.f;
        return;
    }
    float m = -1e30f;
    for (int i = s + lane; i < e; i += 64) m = fmaxf(m, g_all[i]);
#pragma unroll
    for (int d = 32; d; d >>= 1) m = fmaxf(m, __shfl_xor(m, d));
    float sum = 0.f;
    for (int i = s + lane; i < e; i += 64) sum += expf(g_all[i] - m);
#pragma unroll
    for (int d = 32; d; d >>= 1) sum += __shfl_xor(sum, d);
    float inv = 1.f / sum;
    int f = lane & 15, sub = lane >> 4;  // 4 node-slots x 16 features
    float acc = 0.f;
    for (int i = s + sub; i < e; i += 4) {
        float w = expf(g_all[i] - m) * inv;
        acc += w * x[(size_t)i*16 + f];
    }
    acc += __shfl_xor(acc, 16);
    acc += __shfl_xor(acc, 32);
    if (lane < 16) x_att[g*16 + f] = acc;
}

// ---------------- conv1 edge kernel: NNConv(16 -> 32) -----------------------
// per edge: h = relu(ea@w1+b1); msg[o] = sum_i x_src[i]*(sum_k h[k]*w2[k][i*32+o] + b2[i*32+o])
// 2 edges per thread so every w2 LDS broadcast feeds 8 FMAs.
__global__ __launch_bounds__(256) void k_conv1(
    const float* __restrict__ x, const float* __restrict__ ea,
    const int* __restrict__ ei, const float* __restrict__ w1,
    const float* __restrict__ b1, const float* __restrict__ w2,
    const float* __restrict__ b2, float* __restrict__ agg)
{
    __shared__ float  s_w1[96];
    __shared__ float  s_b1[16];
    __shared__ float4 s_w2[2048];   // [16][128] float4  (w2 row k = 512 floats)
    __shared__ float4 s_b2[128];
    const int tid = threadIdx.x;
    for (int i = tid; i < 2048; i += 256) s_w2[i] = ((const float4*)w2)[i];
    for (int i = tid; i < 96;   i += 256) s_w1[i] = w1[i];
    if (tid < 16)  s_b1[tid] = b1[tid];
    if (tid < 128) s_b2[tid] = ((const float4*)b2)[tid];
    __syncthreads();

    const int e0 = blockIdx.x * 512 + tid;
    const int e1 = e0 + 256;

    float a0[6], a1[6];
#pragma unroll
    for (int t = 0; t < 6; ++t) { a0[t] = ea[(size_t)e0*6 + t]; a1[t] = ea[(size_t)e1*6 + t]; }

    float h0[16], h1[16];
#pragma unroll
    for (int j = 0; j < 16; ++j) {
        float acc0 = s_b1[j], acc1 = s_b1[j];
#pragma unroll
        for (int t = 0; t < 6; ++t) {
            float w = s_w1[t*16 + j];
            acc0 += a0[t] * w;
            acc1 += a1[t] * w;
        }
        h0[j] = fmaxf(acc0, 0.f);
        h1[j] = fmaxf(acc1, 0.f);
    }

    const int s0 = ei[e0], s1 = ei[e1];
    const int d0 = ei[NE + e0], d1 = ei[NE + e1];
    const float* xp0 = x + (size_t)s0 * 16;
    const float* xp1 = x + (size_t)s1 * 16;

    float4 m0[8], m1[8];
#pragma unroll
    for (int q = 0; q < 8; ++q) {
        m0[q] = make_float4(0.f, 0.f, 0.f, 0.f);
        m1[q] = make_float4(0.f, 0.f, 0.f, 0.f);
    }

    for (int i = 0; i < 16; ++i) {          // runtime loop; x re-read (L1-resident line)
        float xi0 = xp0[i], xi1 = xp1[i];
        const float4* wrow = s_w2 + i*8;
        const float4* brow = s_b2 + i*8;
#pragma unroll
        for (int q = 0; q < 8; ++q) {
            float4 wd0 = brow[q];
            float4 wd1 = wd0;
#pragma unroll
            for (int k = 0; k < 16; ++k) {
                float4 w = wrow[k*128 + q];
                wd0.x += h0[k]*w.x; wd0.y += h0[k]*w.y; wd0.z += h0[k]*w.z; wd0.w += h0[k]*w.w;
                wd1.x += h1[k]*w.x; wd1.y += h1[k]*w.y; wd1.z += h1[k]*w.z; wd1.w += h1[k]*w.w;
            }
            m0[q].x += xi0*wd0.x; m0[q].y += xi0*wd0.y; m0[q].z += xi0*wd0.z; m0[q].w += xi0*wd0.w;
            m1[q].x += xi1*wd1.x; m1[q].y += xi1*wd1.y; m1[q].z += xi1*wd1.z; m1[q].w += xi1*wd1.w;
        }
    }

    float* p0 = agg + (size_t)d0 * 32;
    float* p1 = agg + (size_t)d1 * 32;
#pragma unroll
    for (int q = 0; q < 8; ++q) {
        atomicAdd(p0 + 4*q + 0, m0[q].x);
        atomicAdd(p0 + 4*q + 1, m0[q].y);
        atomicAdd(p0 + 4*q + 2, m0[q].z);
        atomicAdd(p0 + 4*q + 3, m0[q].w);
    }
#pragma unroll
    for (int q = 0; q < 8; ++q) {
        atomicAdd(p1 + 4*q + 0, m1[q].x);
        atomicAdd(p1 + 4*q + 1, m1[q].y);
        atomicAdd(p1 + 4*q + 2, m1[q].z);
        atomicAdd(p1 + 4*q + 3, m1[q].w);
    }
}

// ---------------- node update 1: h1 = relu(agg1 + x@root1 + bias1) ----------
__global__ __launch_bounds__(256) void k_node1(
    const float* __restrict__ x, const float* __restrict__ root,
    const float* __restrict__ bias, float* __restrict__ agg)
{
    __shared__ float s_r[512];   // [16][32]
    __shared__ float s_b[32];
    int tid = threadIdx.x;
    for (int i = tid; i < 512; i += 256) s_r[i] = root[i];
    if (tid < 32) s_b[tid] = bias[tid];
    __syncthreads();
    int n = blockIdx.x * 256 + tid;
    if (n >= NN) return;
    float xv[16];
    const float4* xp = (const float4*)(x + (size_t)n * 16);
#pragma unroll
    for (int i = 0; i < 4; ++i) {
        float4 t = xp[i];
        xv[4*i] = t.x; xv[4*i+1] = t.y; xv[4*i+2] = t.z; xv[4*i+3] = t.w;
    }
    const float4* s_r4 = (const float4*)s_r;   // [16][8]
    float4* ap = (float4*)(agg + (size_t)n * 32);
#pragma unroll
    for (int q = 0; q < 8; ++q) {
        float4 r = make_float4(s_b[4*q], s_b[4*q+1], s_b[4*q+2], s_b[4*q+3]);
#pragma unroll
        for (int i = 0; i < 16; ++i) {
            float4 w = s_r4[i*8 + q];
            r.x += xv[i]*w.x; r.y += xv[i]*w.y; r.z += xv[i]*w.z; r.w += xv[i]*w.w;
        }
        float4 a = ap[q];
        a.x = fmaxf(a.x + r.x, 0.f);
        a.y = fmaxf(a.y + r.y, 0.f);
        a.z = fmaxf(a.z + r.z, 0.f);
        a.w = fmaxf(a.w + r.w, 0.f);
        ap[q] = a;
    }
}

// ---------------- conv2 edge kernel: NNConv(32 -> 16) -----------------------
__global__ __launch_bounds__(256) void k_conv2(
    const float* __restrict__ x, const float* __restrict__ ea,
    const int* __restrict__ ei, const float* __restrict__ w1,
    const float* __restrict__ b1, const float* __restrict__ w2,
    const float* __restrict__ b2, float* __restrict__ agg)
{
    __shared__ float  s_w1[96];
    __shared__ float  s_b1[16];
    __shared__ float4 s_w2[2048];   // [16][128] float4 (row = 512 floats = 32in x 16out)
    __shared__ float4 s_b2[128];
    const int tid = threadIdx.x;
    for (int i = tid; i < 2048; i += 256) s_w2[i] = ((const float4*)w2)[i];
    for (int i = tid; i < 96;   i += 256) s_w1[i] = w1[i];
    if (tid < 16)  s_b1[tid] = b1[tid];
    if (tid < 128) s_b2[tid] = ((const float4*)b2)[tid];
    __syncthreads();

    const int e0 = blockIdx.x * 512 + tid;
    const int e1 = e0 + 256;

    float a0[6], a1[6];
#pragma unroll
    for (int t = 0; t < 6; ++t) { a0[t] = ea[(size_t)e0*6 + t]; a1[t] = ea[(size_t)e1*6 + t]; }

    float h0[16], h1[16];
#pragma unroll
    for (int j = 0; j < 16; ++j) {
        float acc0 = s_b1[j], acc1 = s_b1[j];
#pragma unroll
        for (int t = 0; t < 6; ++t) {
            float w = s_w1[t*16 + j];
            acc0 += a0[t] * w;
            acc1 += a1[t] * w;
        }
        h0[j] = fmaxf(acc0, 0.f);
        h1[j] = fmaxf(acc1, 0.f);
    }

    const int s0 = ei[e0], s1 = ei[e1];
    const int d0 = ei[NE + e0], d1 = ei[NE + e1];
    const float* xp0 = x + (size_t)s0 * 32;
    const float* xp1 = x + (size_t)s1 * 32;

    float4 m0[4], m1[4];
#pragma unroll
    for (int q = 0; q < 4; ++q) {
        m0[q] = make_float4(0.f, 0.f, 0.f, 0.f);
        m1[q] = make_float4(0.f, 0.f, 0.f, 0.f);
    }

    for (int i = 0; i < 32; ++i) {
        float xi0 = xp0[i], xi1 = xp1[i];
        const float4* wrow = s_w2 + i*4;
        const float4* brow = s_b2 + i*4;
#pragma unroll
        for (int q = 0; q < 4; ++q) {
            float4 wd0 = brow[q];
            float4 wd1 = wd0;
#pragma unroll
            for (int k = 0; k < 16; ++k) {
                float4 w = wrow[k*128 + q];
                wd0.x += h0[k]*w.x; wd0.y += h0[k]*w.y; wd0.z += h0[k]*w.z; wd0.w += h0[k]*w.w;
                wd1.x += h1[k]*w.x; wd1.y += h1[k]*w.y; wd1.z += h1[k]*w.z; wd1.w += h1[k]*w.w;
            }
            m0[q].x += xi0*wd0.x; m0[q].y += xi0*wd0.y; m0[q].z += xi0*wd0.z; m0[q].w += xi0*wd0.w;
            m1[q].x += xi1*wd1.x; m1[q].y += xi1*wd1.y; m1[q].z += xi1*wd1.z; m1[q].w += xi1*wd1.w;
        }
    }

    float* p0 = agg + (size_t)d0 * 16;
    float* p1 = agg + (size_t)d1 * 16;
#pragma unroll
    for (int q = 0; q < 4; ++q) {
        atomicAdd(p0 + 4*q + 0, m0[q].x);
        atomicAdd(p0 + 4*q + 1, m0[q].y);
        atomicAdd(p0 + 4*q + 2, m0[q].z);
        atomicAdd(p0 + 4*q + 3, m0[q].w);
    }
#pragma unroll
    for (int q = 0; q < 4; ++q) {
        atomicAdd(p1 + 4*q + 0, m1[q].x);
        atomicAdd(p1 + 4*q + 1, m1[q].y);
        atomicAdd(p1 + 4*q + 2, m1[q].z);
        atomicAdd(p1 + 4*q + 3, m1[q].w);
    }
}

// ---------------- node update 2: h2 = relu(agg2 + h1@root2 + bias2) ---------
__global__ __launch_bounds__(256) void k_node2(
    const float* __restrict__ h1, const float* __restrict__ root,
    const float* __restrict__ bias, float* __restrict__ agg)
{
    __shared__ float s_r[512];   // [32][16]
    __shared__ float s_b[16];
    int tid = threadIdx.x;
    for (int i = tid; i < 512; i += 256) s_r[i] = root[i];
    if (tid < 16) s_b[tid] = bias[tid];
    __syncthreads();
    int n = blockIdx.x * 256 + tid;
    if (n >= NN) return;
    float xv[32];
    const float4* xp = (const float4*)(h1 + (size_t)n * 32);
#pragma unroll
    for (int i = 0; i < 8; ++i) {
        float4 t = xp[i];
        xv[4*i] = t.x; xv[4*i+1] = t.y; xv[4*i+2] = t.z; xv[4*i+3] = t.w;
    }
    const float4* s_r4 = (const float4*)s_r;   // [32][4]
    float4* ap = (float4*)(agg + (size_t)n * 16);
#pragma unroll
    for (int q = 0; q < 4; ++q) {
        float4 r = make_float4(s_b[4*q], s_b[4*q+1], s_b[4*q+2], s_b[4*q+3]);
#pragma unroll
        for (int i = 0; i < 32; ++i) {
            float4 w = s_r4[i*4 + q];
            r.x += xv[i]*w.x; r.y += xv[i]*w.y; r.z += xv[i]*w.z; r.w += xv[i]*w.w;
        }
        float4 a = ap[q];
        a.x = fmaxf(a.x + r.x, 0.f);
        a.y = fmaxf(a.y + r.y, 0.f);
        a.z = fmaxf(a.z + r.z, 0.f);
        a.w = fmaxf(a.w + r.w, 0.f);
        ap[q] = a;
    }
}

// ---------------- mean pool + concat + head ---------------------------------
__global__ __launch_bounds__(64) void k_head(
    const float* __restrict__ h2, const float* __restrict__ x_att,
    const int* __restrict__ offs,
    const float* __restrict__ l1w, const float* __restrict__ l1b,
    const float* __restrict__ l2w, const float* __restrict__ l2b,
    float* __restrict__ out)
{
    int g = blockIdx.x;
    int lane = threadIdx.x;
    int s = offs[g], e = offs[g + 1];
    __shared__ float v[32];
    __shared__ float hmid[8];
    int f = lane & 15, sub = lane >> 4;
    float acc = 0.f;
    for (int i = s + sub; i < e; i += 4) acc += h2[(size_t)i*16 + f];
    acc += __shfl_xor(acc, 16);
    acc += __shfl_xor(acc, 32);
    float cnt = fmaxf((float)(e - s), 1.0f);
    if (lane < 16) {
        v[lane]      = acc / cnt;
        v[16 + lane] = x_att[g*16 + lane];
    }
    __syncthreads();
    if (lane < 8) {
        float a = l1b[lane];
#pragma unroll
        for (int i = 0; i < 32; ++i) a += v[i] * l1w[i*8 + lane];
        hmid[lane] = a;
    }
    __syncthreads();
    if (lane == 0) {
        float a = l2b[0];
#pragma unroll
        for (int j = 0; j < 8; ++j) a += hmid[j] * l2w[j];
        out[g] = a;
    }
}

extern "C" void kernel_launch(void* const* d_in, const int* in_sizes, int n_in,
                              void* d_out, int out_size, void* d_ws, size_t ws_size,
                              hipStream_t stream) {
    const float* x_p    = (const float*)d_in[0];
    const float* ea_p   = (const float*)d_in[2];
    const int*   ei     = (const int*)d_in[4];
    const int*   batch  = (const int*)d_in[5];
    const float* nn1_w1 = (const float*)d_in[6];
    const float* nn1_b1 = (const float*)d_in[7];
    const float* nn1_w2 = (const float*)d_in[8];
    const float* nn1_b2 = (const float*)d_in[9];
    const float* root1  = (const float*)d_in[10];
    const float* bias1  = (const float*)d_in[11];
    const float* nn2_w1 = (const float*)d_in[12];
    const float* nn2_b1 = (const float*)d_in[13];
    const float* nn2_w2 = (const float*)d_in[14];
    const float* nn2_b2 = (const float*)d_in[15];
    const float* root2  = (const float*)d_in[16];
    const float* bias2  = (const float*)d_in[17];
    const float* gw1    = (const float*)d_in[18];
    const float* gb1    = (const float*)d_in[19];
    const float* gw2    = (const float*)d_in[20];
    const float* gb2    = (const float*)d_in[21];
    const float* l1w    = (const float*)d_in[22];
    const float* l1b    = (const float*)d_in[23];
    const float* l2w    = (const float*)d_in[24];
    const float* l2b    = (const float*)d_in[25];

    float* agg1  = (float*)d_ws;                 // NN*32
    float* agg2  = agg1 + (size_t)NN * 32;       // NN*16
    float* g_all = agg2 + (size_t)NN * 16;       // NN
    float* x_att = g_all + NN;                   // NG*16
    int*   offs  = (int*)(x_att + (size_t)NG * 16);  // NG+1

    hipMemsetAsync(agg1, 0, (size_t)NN * 32 * sizeof(float), stream);
    hipMemsetAsync(agg2, 0, (size_t)NN * 16 * sizeof(float), stream);

    k_gate<<<NN/256, 256, 0, stream>>>(x_p, gw1, gb1, gw2, gb2, g_all);
    k_offsets<<<(NG + 1 + 255)/256, 256, 0, stream>>>(batch, offs);
    k_attpool<<<NG, 64, 0, stream>>>(x_p, g_all, offs, x_att);
    k_conv1<<<NE/512, 256, 0, stream>>>(x_p, ea_p, ei, nn1_w1, nn1_b1, nn1_w2, nn1_b2, agg1);
    k_node1<<<NN/256, 256, 0, stream>>>(x_p, root1, bias1, agg1);
    k_conv2<<<NE/512, 256, 0, stream>>>(agg1, ea_p, ei, nn2_w1, nn2_b1, nn2_w2, nn2_b2, agg2);
    k_node2<<<NN/256, 256, 0, stream>>>(agg1, root2, bias2, agg2);
    k_head<<<NG, 64, 0, stream>>>(agg2, x_att, offs, l1w, l1b, l2w, l2b, (float*)d_out);
}

// Round 2
// 225.753 us; speedup vs baseline: 3.5737x; 3.5737x over previous
//
#include <hip/hip_runtime.h>

#define NN 65536
#define NE 262144
#define NG 2048

// ---------------- gate logits: g_all[n] = (relu(x@gw1+gb1))@gw2 + gb2 --------
__global__ __launch_bounds__(256) void k_gate(const float* __restrict__ x,
    const float* __restrict__ gw1, const float* __restrict__ gb1,
    const float* __restrict__ gw2, const float* __restrict__ gb2,
    float* __restrict__ g_all)
{
    __shared__ float s_w[256];
    __shared__ float s_b[16];
    __shared__ float s_w2[16];
    __shared__ float s_b2;
    int tid = threadIdx.x;
    s_w[tid & 255] = gw1[tid & 255];
    if (tid < 16) { s_b[tid] = gb1[tid]; s_w2[tid] = gw2[tid]; }
    if (tid == 0) s_b2 = gb2[0];
    __syncthreads();
    int n = blockIdx.x * 256 + tid;
    if (n >= NN) return;
    float xv[16];
    const float4* xp = (const float4*)(x + (size_t)n * 16);
#pragma unroll
    for (int i = 0; i < 4; ++i) {
        float4 t = xp[i];
        xv[4*i] = t.x; xv[4*i+1] = t.y; xv[4*i+2] = t.z; xv[4*i+3] = t.w;
    }
    float g = s_b2;
#pragma unroll
    for (int j = 0; j < 16; ++j) {
        float a = s_b[j];
#pragma unroll
        for (int i = 0; i < 16; ++i) a += xv[i] * s_w[i*16 + j];
        g += fmaxf(a, 0.f) * s_w2[j];
    }
    g_all[n] = g;
}

// ---------------- graph boundary offsets (batch is sorted) ------------------
__global__ void k_goffsets(const int* __restrict__ batch, int* __restrict__ goffs)
{
    int g = blockIdx.x * blockDim.x + threadIdx.x;
    if (g > NG) return;
    int lo = 0, hi = NN;
    while (lo < hi) {
        int mid = (lo + hi) >> 1;
        if (batch[mid] < g) lo = mid + 1; else hi = mid;
    }
    goffs[g] = lo;
}

// ---------------- attention pool over raw x ---------------------------------
__global__ __launch_bounds__(64) void k_attpool(const float* __restrict__ x,
    const float* __restrict__ g_all, const int* __restrict__ goffs,
    float* __restrict__ x_att)
{
    int g = blockIdx.x;
    int lane = threadIdx.x;
    int s = goffs[g], e = goffs[g + 1];
    if (s >= e) {
        if (lane < 16) x_att[g*16 + lane] = 0.f;
        return;
    }
    float m = -1e30f;
    for (int i = s + lane; i < e; i += 64) m = fmaxf(m, g_all[i]);
#pragma unroll
    for (int d = 32; d; d >>= 1) m = fmaxf(m, __shfl_xor(m, d));
    float sum = 0.f;
    for (int i = s + lane; i < e; i += 64) sum += expf(g_all[i] - m);
#pragma unroll
    for (int d = 32; d; d >>= 1) sum += __shfl_xor(sum, d);
    float inv = 1.f / sum;
    int f = lane & 15, sub = lane >> 4;  // 4 node-slots x 16 features
    float acc = 0.f;
    for (int i = s + sub; i < e; i += 4) {
        float w = expf(g_all[i] - m) * inv;
        acc += w * x[(size_t)i*16 + f];
    }
    acc += __shfl_xor(acc, 16);
    acc += __shfl_xor(acc, 32);
    if (lane < 16) x_att[g*16 + f] = acc;
}

// ---------------- CSR build: histogram / scan / scatter ----------------------
__global__ __launch_bounds__(256) void k_hist(const int* __restrict__ ei, int* __restrict__ cnt)
{
    int e = blockIdx.x * 256 + threadIdx.x;
    if (e >= NE) return;
    atomicAdd(&cnt[ei[NE + e]], 1);
}

__global__ __launch_bounds__(256) void k_scan_blk(const int* __restrict__ cnt,
    int* __restrict__ offs, int* __restrict__ bsum)
{
    __shared__ int s[256];
    int t = threadIdx.x, b = blockIdx.x;
    int v = cnt[b*256 + t];
    s[t] = v;
    __syncthreads();
#pragma unroll
    for (int d = 1; d < 256; d <<= 1) {
        int add = (t >= d) ? s[t - d] : 0;
        __syncthreads();
        s[t] += add;
        __syncthreads();
    }
    offs[b*256 + t] = s[t] - v;          // exclusive within block
    if (t == 255) bsum[b] = s[255];
}

__global__ __launch_bounds__(256) void k_scan_top(const int* __restrict__ bsum,
    int* __restrict__ boff)
{
    __shared__ int s[256];
    int t = threadIdx.x;
    int v = bsum[t];
    s[t] = v;
    __syncthreads();
#pragma unroll
    for (int d = 1; d < 256; d <<= 1) {
        int add = (t >= d) ? s[t - d] : 0;
        __syncthreads();
        s[t] += add;
        __syncthreads();
    }
    boff[t] = s[t] - v;                  // exclusive
}

__global__ __launch_bounds__(256) void k_scan_add(int* __restrict__ offs,
    const int* __restrict__ boff)
{
    int i = blockIdx.x * 256 + threadIdx.x;
    if (i == 0) offs[NN] = NE;
    if (i >= NN) return;
    offs[i] += boff[i >> 8];
}

__global__ __launch_bounds__(256) void k_scatter(const int* __restrict__ ei,
    const int* __restrict__ offs, int* __restrict__ cur, int* __restrict__ eperm)
{
    int e = blockIdx.x * 256 + threadIdx.x;
    if (e >= NE) return;
    int d = ei[NE + e];
    int pos = offs[d] + atomicAdd(&cur[d], 1);
    eperm[pos] = e;
}

// ---------------- conv1 edge kernel: NNConv(16 -> 32), msg output ------------
// per edge: h = relu(ea@w1+b1); msg[o] = sum_i x_src[i]*(sum_k h[k]*w2[k][i*32+o] + b2[i*32+o])
// 2 edges per thread so every w2 LDS broadcast feeds 8 FMAs. No atomics: msg row
// is stored at the dst-sorted position p, reduced later per node.
__global__ __launch_bounds__(256) void k_conv1(
    const float* __restrict__ x, const float* __restrict__ ea,
    const int* __restrict__ ei, const int* __restrict__ eperm,
    const float* __restrict__ w1, const float* __restrict__ b1,
    const float* __restrict__ w2, const float* __restrict__ b2,
    float* __restrict__ msg)
{
    __shared__ float  s_w1[96];
    __shared__ float  s_b1[16];
    __shared__ float4 s_w2[2048];   // [16][128] float4  (w2 row k = 512 floats)
    __shared__ float4 s_b2[128];
    const int tid = threadIdx.x;
    for (int i = tid; i < 2048; i += 256) s_w2[i] = ((const float4*)w2)[i];
    for (int i = tid; i < 96;   i += 256) s_w1[i] = w1[i];
    if (tid < 16)  s_b1[tid] = b1[tid];
    if (tid < 128) s_b2[tid] = ((const float4*)b2)[tid];
    __syncthreads();

    const int p0 = blockIdx.x * 512 + tid;
    const int p1 = p0 + 256;
    const int e0 = eperm[p0], e1 = eperm[p1];

    float a0[6], a1[6];
#pragma unroll
    for (int t = 0; t < 6; ++t) { a0[t] = ea[(size_t)e0*6 + t]; a1[t] = ea[(size_t)e1*6 + t]; }

    float h0[16], h1[16];
#pragma unroll
    for (int j = 0; j < 16; ++j) {
        float acc0 = s_b1[j], acc1 = s_b1[j];
#pragma unroll
        for (int t = 0; t < 6; ++t) {
            float w = s_w1[t*16 + j];
            acc0 += a0[t] * w;
            acc1 += a1[t] * w;
        }
        h0[j] = fmaxf(acc0, 0.f);
        h1[j] = fmaxf(acc1, 0.f);
    }

    const int s0 = ei[e0], s1 = ei[e1];
    const float* xp0 = x + (size_t)s0 * 16;
    const float* xp1 = x + (size_t)s1 * 16;

    float4 m0[8], m1[8];
#pragma unroll
    for (int q = 0; q < 8; ++q) {
        m0[q] = make_float4(0.f, 0.f, 0.f, 0.f);
        m1[q] = make_float4(0.f, 0.f, 0.f, 0.f);
    }

    for (int i = 0; i < 16; ++i) {          // runtime loop; x re-read (L1-resident line)
        float xi0 = xp0[i], xi1 = xp1[i];
        const float4* wrow = s_w2 + i*8;
        const float4* brow = s_b2 + i*8;
#pragma unroll
        for (int q = 0; q < 8; ++q) {
            float4 wd0 = brow[q];
            float4 wd1 = wd0;
#pragma unroll
            for (int k = 0; k < 16; ++k) {
                float4 w = wrow[k*128 + q];
                wd0.x += h0[k]*w.x; wd0.y += h0[k]*w.y; wd0.z += h0[k]*w.z; wd0.w += h0[k]*w.w;
                wd1.x += h1[k]*w.x; wd1.y += h1[k]*w.y; wd1.z += h1[k]*w.z; wd1.w += h1[k]*w.w;
            }
            m0[q].x += xi0*wd0.x; m0[q].y += xi0*wd0.y; m0[q].z += xi0*wd0.z; m0[q].w += xi0*wd0.w;
            m1[q].x += xi1*wd1.x; m1[q].y += xi1*wd1.y; m1[q].z += xi1*wd1.z; m1[q].w += xi1*wd1.w;
        }
    }

    float4* mp0 = (float4*)(msg + (size_t)p0 * 32);
    float4* mp1 = (float4*)(msg + (size_t)p1 * 32);
#pragma unroll
    for (int q = 0; q < 8; ++q) mp0[q] = m0[q];
#pragma unroll
    for (int q = 0; q < 8; ++q) mp1[q] = m1[q];
}

// ---------------- reduce1: h1 = relu(segsum(msg) + x@root1 + bias1) ----------
__global__ __launch_bounds__(256) void k_reduce1(
    const float* __restrict__ msg, const int* __restrict__ offs,
    const float* __restrict__ x, const float* __restrict__ root,
    const float* __restrict__ bias, float* __restrict__ h1)
{
    __shared__ float s_r[512];   // [16][32]
    __shared__ float s_b[32];
    int tid = threadIdx.x;
    for (int i = tid; i < 512; i += 256) s_r[i] = root[i];
    if (tid < 32) s_b[tid] = bias[tid];
    __syncthreads();
    int gid = blockIdx.x * 256 + tid;
    int n = gid >> 3, q = gid & 7;       // 8 float4 columns per node
    int s = offs[n], e = offs[n + 1];
    float4 acc = make_float4(s_b[4*q], s_b[4*q+1], s_b[4*q+2], s_b[4*q+3]);
    const float4* s_r4 = (const float4*)s_r;   // [16][8]
    const float* xp = x + (size_t)n * 16;
#pragma unroll
    for (int i = 0; i < 16; ++i) {
        float xi = xp[i];
        float4 w = s_r4[i*8 + q];
        acc.x += xi*w.x; acc.y += xi*w.y; acc.z += xi*w.z; acc.w += xi*w.w;
    }
    for (int p = s; p < e; ++p) {
        float4 mr = ((const float4*)(msg + (size_t)p * 32))[q];
        acc.x += mr.x; acc.y += mr.y; acc.z += mr.z; acc.w += mr.w;
    }
    acc.x = fmaxf(acc.x, 0.f); acc.y = fmaxf(acc.y, 0.f);
    acc.z = fmaxf(acc.z, 0.f); acc.w = fmaxf(acc.w, 0.f);
    ((float4*)(h1 + (size_t)n * 32))[q] = acc;
}

// ---------------- conv2 edge kernel: NNConv(32 -> 16), msg output ------------
__global__ __launch_bounds__(256) void k_conv2(
    const float* __restrict__ x, const float* __restrict__ ea,
    const int* __restrict__ ei, const int* __restrict__ eperm,
    const float* __restrict__ w1, const float* __restrict__ b1,
    const float* __restrict__ w2, const float* __restrict__ b2,
    float* __restrict__ msg)
{
    __shared__ float  s_w1[96];
    __shared__ float  s_b1[16];
    __shared__ float4 s_w2[2048];   // [32][64] float4 (row i = 16 outs => 4 float4)
    __shared__ float4 s_b2[128];
    const int tid = threadIdx.x;
    for (int i = tid; i < 2048; i += 256) s_w2[i] = ((const float4*)w2)[i];
    for (int i = tid; i < 96;   i += 256) s_w1[i] = w1[i];
    if (tid < 16)  s_b1[tid] = b1[tid];
    if (tid < 128) s_b2[tid] = ((const float4*)b2)[tid];
    __syncthreads();

    const int p0 = blockIdx.x * 512 + tid;
    const int p1 = p0 + 256;
    const int e0 = eperm[p0], e1 = eperm[p1];

    float a0[6], a1[6];
#pragma unroll
    for (int t = 0; t < 6; ++t) { a0[t] = ea[(size_t)e0*6 + t]; a1[t] = ea[(size_t)e1*6 + t]; }

    float h0[16], h1[16];
#pragma unroll
    for (int j = 0; j < 16; ++j) {
        float acc0 = s_b1[j], acc1 = s_b1[j];
#pragma unroll
        for (int t = 0; t < 6; ++t) {
            float w = s_w1[t*16 + j];
            acc0 += a0[t] * w;
            acc1 += a1[t] * w;
        }
        h0[j] = fmaxf(acc0, 0.f);
        h1[j] = fmaxf(acc1, 0.f);
    }

    const int s0 = ei[e0], s1 = ei[e1];
    const float* xp0 = x + (size_t)s0 * 32;
    const float* xp1 = x + (size_t)s1 * 32;

    float4 m0[4], m1[4];
#pragma unroll
    for (int q = 0; q < 4; ++q) {
        m0[q] = make_float4(0.f, 0.f, 0.f, 0.f);
        m1[q] = make_float4(0.f, 0.f, 0.f, 0.f);
    }

    for (int i = 0; i < 32; ++i) {
        float xi0 = xp0[i], xi1 = xp1[i];
        const float4* wrow = s_w2 + i*4;
        const float4* brow = s_b2 + i*4;
#pragma unroll
        for (int q = 0; q < 4; ++q) {
            float4 wd0 = brow[q];
            float4 wd1 = wd0;
#pragma unroll
            for (int k = 0; k < 16; ++k) {
                float4 w = wrow[k*128 + q];
                wd0.x += h0[k]*w.x; wd0.y += h0[k]*w.y; wd0.z += h0[k]*w.z; wd0.w += h0[k]*w.w;
                wd1.x += h1[k]*w.x; wd1.y += h1[k]*w.y; wd1.z += h1[k]*w.z; wd1.w += h1[k]*w.w;
            }
            m0[q].x += xi0*wd0.x; m0[q].y += xi0*wd0.y; m0[q].z += xi0*wd0.z; m0[q].w += xi0*wd0.w;
            m1[q].x += xi1*wd1.x; m1[q].y += xi1*wd1.y; m1[q].z += xi1*wd1.z; m1[q].w += xi1*wd1.w;
        }
    }

    float4* mp0 = (float4*)(msg + (size_t)p0 * 16);
    float4* mp1 = (float4*)(msg + (size_t)p1 * 16);
#pragma unroll
    for (int q = 0; q < 4; ++q) mp0[q] = m0[q];
#pragma unroll
    for (int q = 0; q < 4; ++q) mp1[q] = m1[q];
}

// ---------------- reduce2: h2 = relu(segsum(msg) + h1@root2 + bias2) ---------
__global__ __launch_bounds__(256) void k_reduce2(
    const float* __restrict__ msg, const int* __restrict__ offs,
    const float* __restrict__ h1, const float* __restrict__ root,
    const float* __restrict__ bias, float* __restrict__ h2)
{
    __shared__ float s_r[512];   // [32][16]
    __shared__ float s_b[16];
    int tid = threadIdx.x;
    for (int i = tid; i < 512; i += 256) s_r[i] = root[i];
    if (tid < 16) s_b[tid] = bias[tid];
    __syncthreads();
    int gid = blockIdx.x * 256 + tid;
    int n = gid >> 2, q = gid & 3;       // 4 float4 columns per node
    int s = offs[n], e = offs[n + 1];
    float4 acc = make_float4(s_b[4*q], s_b[4*q+1], s_b[4*q+2], s_b[4*q+3]);
    const float4* s_r4 = (const float4*)s_r;   // [32][4]
    const float* xp = h1 + (size_t)n * 32;
#pragma unroll
    for (int i = 0; i < 32; ++i) {
        float xi = xp[i];
        float4 w = s_r4[i*4 + q];
        acc.x += xi*w.x; acc.y += xi*w.y; acc.z += xi*w.z; acc.w += xi*w.w;
    }
    for (int p = s; p < e; ++p) {
        float4 mr = ((const float4*)(msg + (size_t)p * 16))[q];
        acc.x += mr.x; acc.y += mr.y; acc.z += mr.z; acc.w += mr.w;
    }
    acc.x = fmaxf(acc.x, 0.f); acc.y = fmaxf(acc.y, 0.f);
    acc.z = fmaxf(acc.z, 0.f); acc.w = fmaxf(acc.w, 0.f);
    ((float4*)(h2 + (size_t)n * 16))[q] = acc;
}

// ---------------- mean pool + concat + head ---------------------------------
__global__ __launch_bounds__(64) void k_head(
    const float* __restrict__ h2, const float* __restrict__ x_att,
    const int* __restrict__ goffs,
    const float* __restrict__ l1w, const float* __restrict__ l1b,
    const float* __restrict__ l2w, const float* __restrict__ l2b,
    float* __restrict__ out)
{
    int g = blockIdx.x;
    int lane = threadIdx.x;
    int s = goffs[g], e = goffs[g + 1];
    __shared__ float v[32];
    __shared__ float hmid[8];
    int f = lane & 15, sub = lane >> 4;
    float acc = 0.f;
    for (int i = s + sub; i < e; i += 4) acc += h2[(size_t)i*16 + f];
    acc += __shfl_xor(acc, 16);
    acc += __shfl_xor(acc, 32);
    float cnt = fmaxf((float)(e - s), 1.0f);
    if (lane < 16) {
        v[lane]      = acc / cnt;
        v[16 + lane] = x_att[g*16 + lane];
    }
    __syncthreads();
    if (lane < 8) {
        float a = l1b[lane];
#pragma unroll
        for (int i = 0; i < 32; ++i) a += v[i] * l1w[i*8 + lane];
        hmid[lane] = a;
    }
    __syncthreads();
    if (lane == 0) {
        float a = l2b[0];
#pragma unroll
        for (int j = 0; j < 8; ++j) a += hmid[j] * l2w[j];
        out[g] = a;
    }
}

extern "C" void kernel_launch(void* const* d_in, const int* in_sizes, int n_in,
                              void* d_out, int out_size, void* d_ws, size_t ws_size,
                              hipStream_t stream) {
    const float* x_p    = (const float*)d_in[0];
    const float* ea_p   = (const float*)d_in[2];
    const int*   ei     = (const int*)d_in[4];
    const int*   batch  = (const int*)d_in[5];
    const float* nn1_w1 = (const float*)d_in[6];
    const float* nn1_b1 = (const float*)d_in[7];
    const float* nn1_w2 = (const float*)d_in[8];
    const float* nn1_b2 = (const float*)d_in[9];
    const float* root1  = (const float*)d_in[10];
    const float* bias1  = (const float*)d_in[11];
    const float* nn2_w1 = (const float*)d_in[12];
    const float* nn2_b1 = (const float*)d_in[13];
    const float* nn2_w2 = (const float*)d_in[14];
    const float* nn2_b2 = (const float*)d_in[15];
    const float* root2  = (const float*)d_in[16];
    const float* bias2  = (const float*)d_in[17];
    const float* gw1    = (const float*)d_in[18];
    const float* gb1    = (const float*)d_in[19];
    const float* gw2    = (const float*)d_in[20];
    const float* gb2    = (const float*)d_in[21];
    const float* l1w    = (const float*)d_in[22];
    const float* l1b    = (const float*)d_in[23];
    const float* l2w    = (const float*)d_in[24];
    const float* l2b    = (const float*)d_in[25];

    // -------- workspace layout (floats/ints), ~48 MB total --------
    float* h1    = (float*)d_ws;                     // NN*32
    float* h2    = h1 + (size_t)NN * 32;             // NN*16
    float* g_all = h2 + (size_t)NN * 16;             // NN
    float* x_att = g_all + NN;                       // NG*16
    int*   goffs = (int*)(x_att + (size_t)NG * 16);  // NG+1 (pad to 2052)
    int*   offs  = goffs + 2052;                     // NN+1 (pad to 65540)
    int*   cnt   = offs + 65540;                     // NN (hist, then cursor)
    int*   bsum  = cnt + NN;                         // 256
    int*   boff  = bsum + 256;                       // 256
    int*   eperm = boff + 256;                       // NE
    float* msg   = (float*)(eperm + NE);             // NE*32 (conv1), reused NE*16 (conv2)

    // -------- attention pool path --------
    k_gate<<<NN/256, 256, 0, stream>>>(x_p, gw1, gb1, gw2, gb2, g_all);
    k_goffsets<<<(NG + 1 + 255)/256, 256, 0, stream>>>(batch, goffs);
    k_attpool<<<NG, 64, 0, stream>>>(x_p, g_all, goffs, x_att);

    // -------- CSR build over dst --------
    hipMemsetAsync(cnt, 0, (size_t)NN * sizeof(int), stream);
    k_hist<<<NE/256, 256, 0, stream>>>(ei, cnt);
    k_scan_blk<<<NN/256, 256, 0, stream>>>(cnt, offs, bsum);
    k_scan_top<<<1, 256, 0, stream>>>(bsum, boff);
    k_scan_add<<<NN/256, 256, 0, stream>>>(offs, boff);
    hipMemsetAsync(cnt, 0, (size_t)NN * sizeof(int), stream);
    k_scatter<<<NE/256, 256, 0, stream>>>(ei, offs, cnt, eperm);

    // -------- conv1 + fused node update --------
    k_conv1<<<NE/512, 256, 0, stream>>>(x_p, ea_p, ei, eperm,
                                        nn1_w1, nn1_b1, nn1_w2, nn1_b2, msg);
    k_reduce1<<<NN*8/256, 256, 0, stream>>>(msg, offs, x_p, root1, bias1, h1);

    // -------- conv2 + fused node update --------
    k_conv2<<<NE/512, 256, 0, stream>>>(h1, ea_p, ei, eperm,
                                        nn2_w1, nn2_b1, nn2_w2, nn2_b2, msg);
    k_reduce2<<<NN*4/256, 256, 0, stream>>>(msg, offs, h1, root2, bias2, h2);

    // -------- head --------
    k_head<<<NG, 64, 0, stream>>>(h2, x_att, goffs, l1w, l1b, l2w, l2b, (float*)d_out);
}